// Round 3
// baseline (503.705 us; speedup 1.0000x reference)
//
#include <hip/hip_runtime.h>
#include <math.h>

#define BB 2
#define LL 384
#define DD 256
#define HH 8
#define DHH 32

// workspace layout (float offsets)
// q   [B,L,D]          196608
// kk  [B,L,D]          196608   (k projection, flat layout)
// vv  [B,H,L,DH]       196608
// w   [B,L,H,D]        1572864
// cbr [B,L,H]          6144
static const size_t OFF_Q     = 0;
static const size_t OFF_KK    = 196608;
static const size_t OFF_VV    = 393216;
static const size_t OFF_W     = 589824;
static const size_t OFF_CBR   = 2162688;

__device__ __forceinline__ float dot4(float4 a, float4 b) {
    return a.x * b.x + a.y * b.y + a.z * b.z + a.w * b.w;
}

// ---------------------------------------------------------------------------
// A1: projections  y = x @ W^T + b.
// q and k stored flat [B,L,D]; v stored transposed [B,H,L,DH] for PV.
// ---------------------------------------------------------------------------
__global__ __launch_bounds__(256) void k_proj(
    const float* __restrict__ Xq, const float* __restrict__ Xk, const float* __restrict__ Xv,
    const float* __restrict__ Wq, const float* __restrict__ Wk, const float* __restrict__ Wv,
    const float* __restrict__ bq, const float* __restrict__ bk, const float* __restrict__ bv,
    float* __restrict__ oq, float* __restrict__ okk, float* __restrict__ ovv)
{
    int bx = blockIdx.x;
    int mat = bx / 96;
    int rem = bx % 96;
    int b = rem / 48;
    int l0 = (rem % 48) * 8;
    const float* X = (mat == 0) ? Xq : (mat == 1) ? Xk : Xv;
    const float* W = (mat == 0) ? Wq : (mat == 1) ? Wk : Wv;
    const float* bias = (mat == 0) ? bq : (mat == 1) ? bk : bv;

    __shared__ float xs[8 * 256];
    int tid = threadIdx.x;
    {
        const float4* src = (const float4*)(X + (size_t)(b * LL + l0) * DD);
        float4* dst = (float4*)xs;
        dst[tid] = src[tid];
        dst[tid + 256] = src[tid + 256];
    }
    __syncthreads();

    int n = tid;
    float bn = bias[n];
    float acc[8];
#pragma unroll
    for (int l = 0; l < 8; ++l) acc[l] = bn;

    const float4* wrow = (const float4*)(W + (size_t)n * DD);
#pragma unroll 8
    for (int kc = 0; kc < 64; ++kc) {
        float4 wv = wrow[kc];
#pragma unroll
        for (int l = 0; l < 8; ++l) {
            float4 xv = ((const float4*)(xs + l * 256))[kc];
            acc[l] += dot4(wv, xv);
        }
    }

    if (mat <= 1) {
        float* o = (mat == 0) ? oq : okk;
#pragma unroll
        for (int l = 0; l < 8; ++l)
            o[(size_t)(b * LL + l0 + l) * DD + n] = acc[l];
    } else {
        int h = n >> 5, dh = n & 31;
#pragma unroll
        for (int l = 0; l < 8; ++l)
            ovv[((size_t)(b * HH + h) * LL + l0 + l) * DHH + dh] = acc[l];
    }
}

// ---------------------------------------------------------------------------
// A2: w[b,l,h,d] = sum_dh (q+v)[b,l,h*32+dh] * Wr[h*32+dh, d];  cbr = (q+v)·br
// grid 768 = B * (L/4) * 4 hgroups (2 heads each); 256 threads.
// ---------------------------------------------------------------------------
__global__ __launch_bounds__(256) void k_wproj(
    const float* __restrict__ q, const float* __restrict__ vpar,
    const float* __restrict__ Wr, const float* __restrict__ br,
    float* __restrict__ w, float* __restrict__ cbr)
{
    int bx = blockIdx.x;
    int b = bx / 384;
    int rem = bx % 384;
    int l0 = (rem >> 2) * 4;
    int hg = rem & 3;               // 2 heads per block
    int tid = threadIdx.x;
    int gq = tid >> 6;              // l-row within tile (= wave id)
    int lane = tid & 63;

    __shared__ float qv[4][64];     // (q+v) slice for this head-group
    if (lane < 16) {
        const float* qsrc = q + (size_t)(b * LL + l0 + gq) * DD + hg * 64;
        const float* vsrc = vpar + hg * 64;
        float4 t = *(const float4*)(qsrc + lane * 4);
        float4 vv4 = *(const float4*)(vsrc + lane * 4);
        t.x += vv4.x; t.y += vv4.y; t.z += vv4.z; t.w += vv4.w;
        *(float4*)(&qv[gq][lane * 4]) = t;
    }
    __syncthreads();

    int l = l0 + gq;
    int d4 = lane * 4;
    float* wbase = w + ((size_t)(b * LL + l) * HH) * DD + d4;
#pragma unroll
    for (int h2 = 0; h2 < 2; ++h2) {
        int h = hg * 2 + h2;
        float4 acc = make_float4(0.f, 0.f, 0.f, 0.f);
#pragma unroll 8
        for (int dh = 0; dh < 32; ++dh) {
            float s = qv[gq][h2 * 32 + dh];
            float4 wr4 = *(const float4*)(Wr + (size_t)(h * 32 + dh) * DD + d4);
            acc.x += s * wr4.x; acc.y += s * wr4.y; acc.z += s * wr4.z; acc.w += s * wr4.w;
        }
        *(float4*)(wbase + h * DD) = acc;
    }

    if (tid < 8) {
        int rr = tid >> 1, h2 = tid & 1;
        float s = 0.f;
#pragma unroll 8
        for (int dh = 0; dh < 32; ++dh)
            s += qv[rr][h2 * 32 + dh] * br[hg * 64 + h2 * 32 + dh];
        cbr[(size_t)(b * LL + l0 + rr) * HH + hg * 2 + h2] = s;
    }
}

// ---------------------------------------------------------------------------
// C: fused back-end, one block per (b,q).  v3: occupancy + loop-tightness.
// Phase 0: qs = q_row + u (LDS); sld[h][k] = ((q+u)·kk + cbr)*inv - pen
//          (content term pre-computed OUT of the pos loop).
// Phase 1: pure pos stream.  32-lane d-split: lane g=lane&31 owns d-slices
//          {4g, 4g+128} (wr fragment = 64 VGPR, was 128); r=lane>>5 owns
//          k-row; 2 pos dwordx4 loads + 64 FMA + 9-shfl halving butterfly
//          per lane-iter; accumulates posdot*inv into sld.
//          ~120 VGPR -> 3 blocks/CU resident (768 grid = exact fit, no tail).
// Phase 2a: in-block softmax (wave = 2 heads, 6 keys/lane).
// Phase 2b: PV vs L2-resident vv, direct out write.
// ---------------------------------------------------------------------------
__global__ __launch_bounds__(256, 3) void k_bdsoft(
    const float* __restrict__ pos, const float* __restrict__ w,
    const float* __restrict__ q, const float* __restrict__ u,
    const float* __restrict__ kk, const float* __restrict__ cbr,
    const float* __restrict__ mask, const float* __restrict__ vv,
    float* __restrict__ out)
{
    int b = blockIdx.x / LL;
    int qi = blockIdx.x % LL;
    int tid = threadIdx.x;
    int wave = tid >> 6;
    int lane = tid & 63;
    int g = lane & 31;
    int r = lane >> 5;

    __shared__ float sld[8][390];   // [h][k]: score -> attn in place
    __shared__ float qs[256];       // q_row + u

    const float inv = 0.17677669529663687f; // 1/sqrt(32)

    // ---- Phase 0a: qs = q + u
    qs[tid] = q[(size_t)(b * LL + qi) * DD + tid] + u[tid];

    // position-term fragment: 8 heads x 2 d-slices (64 VGPRs)
    const float* wb = w + ((size_t)(b * LL + qi) * HH) * DD + g * 4;
    float4 wr[8][2];
#pragma unroll
    for (int h = 0; h < 8; ++h) {
        wr[h][0] = *(const float4*)(wb + h * DD);
        wr[h][1] = *(const float4*)(wb + h * DD + 128);
    }
    __syncthreads();

    // ---- Phase 0b: content term + cbr + mask -> sld init
    {
        const float* cbp = cbr + (size_t)(b * LL + qi) * HH;
#pragma unroll
        for (int j = 0; j < 12; ++j) {
            int idx = tid + j * 256;        // 0..3071
            int h = idx / 384;
            int k = idx - h * 384;
            const float4* kp = (const float4*)(kk + (size_t)(b * LL + k) * DD + h * 32);
            const float4* qp = (const float4*)(qs + h * 32);
            float acc = 0.f;
#pragma unroll
            for (int jj = 0; jj < 8; ++jj) acc += dot4(kp[jj], qp[jj]);
            float pen = (1.0f - mask[b * LL + k]) * 1e15f;
            sld[h][k] = (acc + cbp[h]) * inv - pen;
        }
    }
    __syncthreads();

    // ---- Phase 1: pos stream, accumulate posdot*inv into sld
    const float* posq = pos + (size_t)(b * LL + qi) * LL * DD + g * 4;
    const float* pr = posq + (size_t)(wave * 2 + r) * DD;
    int krow = wave * 2 + r;
    bool b4 = (g & 16) != 0;
    bool b3 = (g & 8) != 0;
    bool b2 = (g & 4) != 0;
    int hown = g >> 2;
    bool leader = (g & 3) == 0;

#pragma unroll 1
    for (int it = 0; it < 48; ++it) {
        float4 p0 = *(const float4*)(pr);
        float4 p1 = *(const float4*)(pr + 128);
        float acc[8];
#pragma unroll
        for (int h = 0; h < 8; ++h)
            acc[h] = dot4(p0, wr[h][0]) + dot4(p1, wr[h][1]);

        // value-halving butterfly over 32 lanes: 9 shfl total
        float t0[4];
#pragma unroll
        for (int i = 0; i < 4; ++i) {
            float sendv = b4 ? acc[i] : acc[i + 4];
            float keepv = b4 ? acc[i + 4] : acc[i];
            t0[i] = keepv + __shfl_xor(sendv, 16, 64);
        }
        float t1[2];
#pragma unroll
        for (int i = 0; i < 2; ++i) {
            float sendv = b3 ? t0[i] : t0[i + 2];
            float keepv = b3 ? t0[i + 2] : t0[i];
            t1[i] = keepv + __shfl_xor(sendv, 8, 64);
        }
        float sendv = b2 ? t1[0] : t1[1];
        float keepv = b2 ? t1[1] : t1[0];
        float vsum = keepv + __shfl_xor(sendv, 4, 64);
        vsum += __shfl_xor(vsum, 2, 64);
        vsum += __shfl_xor(vsum, 1, 64);

        if (leader)
            sld[hown][krow] += vsum * inv;

        pr += 8 * DD;
        krow += 8;
    }
    __syncthreads();

    // ---- Phase 2a: softmax over k, wave handles 2 heads, 6 keys/lane.
#pragma unroll
    for (int hi = 0; hi < 2; ++hi) {
        int h = wave * 2 + hi;
        float s[6];
#pragma unroll
        for (int j = 0; j < 6; ++j) s[j] = sld[h][lane + 64 * j];
        float m = s[0];
#pragma unroll
        for (int j = 1; j < 6; ++j) m = fmaxf(m, s[j]);
#pragma unroll
        for (int off = 1; off < 64; off <<= 1) m = fmaxf(m, __shfl_xor(m, off, 64));
        float e[6];
        float ls = 0.f;
#pragma unroll
        for (int j = 0; j < 6; ++j) { e[j] = __expf(s[j] - m); ls += e[j]; }
#pragma unroll
        for (int off = 1; off < 64; off <<= 1) ls += __shfl_xor(ls, off, 64);
        float rinv = 1.0f / ls;
#pragma unroll
        for (int j = 0; j < 6; ++j) sld[h][lane + 64 * j] = e[j] * rinv;
    }
    __syncthreads();

    // ---- Phase 2b: PV.  thread = (h, dh); vv L2-resident.
    int h = tid >> 5, dh = tid & 31;
    const float* vp = vv + ((size_t)(b * HH + h) * LL) * DHH + dh;
    float acc = 0.f;
#pragma unroll 8
    for (int k = 0; k < LL; ++k) {
        acc += sld[h][k] * vp[(size_t)k * DHH];
    }
    out[(size_t)(b * LL + qi) * DD + tid] = acc;
}

extern "C" void kernel_launch(void* const* d_in, const int* in_sizes, int n_in,
                              void* d_out, int out_size, void* d_ws, size_t ws_size,
                              hipStream_t stream) {
    const float* key    = (const float*)d_in[0];
    const float* query  = (const float*)d_in[1];
    const float* value  = (const float*)d_in[2];
    const float* pos    = (const float*)d_in[3];
    const float* kmask  = (const float*)d_in[4];
    const float* Wk     = (const float*)d_in[5];
    const float* bk     = (const float*)d_in[6];
    const float* Wq     = (const float*)d_in[7];
    const float* bq     = (const float*)d_in[8];
    const float* Wv     = (const float*)d_in[9];
    const float* bv     = (const float*)d_in[10];
    const float* Wr     = (const float*)d_in[11];
    const float* br     = (const float*)d_in[12];
    const float* u      = (const float*)d_in[13];
    const float* v      = (const float*)d_in[14];
    float* out = (float*)d_out;

    float* ws = (float*)d_ws;
    float* qbuf   = ws + OFF_Q;
    float* kkbuf  = ws + OFF_KK;
    float* vvbuf  = ws + OFF_VV;
    float* wbuf   = ws + OFF_W;
    float* cbrbuf = ws + OFF_CBR;

    k_proj<<<dim3(288), dim3(256), 0, stream>>>(query, key, value, Wq, Wk, Wv,
                                                bq, bk, bv, qbuf, kkbuf, vvbuf);
    k_wproj<<<dim3(768), dim3(256), 0, stream>>>(qbuf, v, Wr, br, wbuf, cbrbuf);
    k_bdsoft<<<dim3(768), dim3(256), 0, stream>>>(pos, wbuf, qbuf, u, kkbuf,
                                                  cbrbuf, kmask, vvbuf, out);
}